// Round 1
// baseline (145.106 us; speedup 1.0000x reference)
//
#include <hip/hip_runtime.h>
#include <math.h>

#define NTH 256
#define TB 8

static constexpr float HLP = 0.9189385332046727f; // 0.5*log(2*pi)

// ws layout (floats):
// [0, 130560)            normalized weights, layers concat (layer l: R=128>>l regions x 64 x 8)
// [130560, 132608)       leafA = exp(-log_sigma)       [256][8]
// [132608, 134656)       leafB = -log_sigma - HLP      [256][8]
// [134656, 134664)       srw   = softmax(root_w)       [8]
static constexpr int NW   = 130560;
static constexpr int AOFF = NW;
static constexpr int BOFF = NW + 2048;
static constexpr int ROFF = NW + 4096;

// ---------------- prep: normalize weights, leaf constants, root softmax ----------------
__global__ __launch_bounds__(256) void spn_prep(
    const float* __restrict__ ls,
    const float* __restrict__ w0, const float* __restrict__ w1,
    const float* __restrict__ w2, const float* __restrict__ w3,
    const float* __restrict__ w4, const float* __restrict__ w5,
    const float* __restrict__ w6, const float* __restrict__ w7,
    const float* __restrict__ root_w,
    float* __restrict__ ws)
{
  const int job = blockIdx.x * blockDim.x + threadIdx.x;
  if (job < 2040) {
    // one softmax over the 64 children for (layer l, region r, mixture k)
    const float* wl[8] = {w0, w1, w2, w3, w4, w5, w6, w7};
    int j = job, l = 0, base = 0, R = 128;
    while (j >= R * 8) { j -= R * 8; base += R * 512; R >>= 1; ++l; }
    const int r = j >> 3, k = j & 7;
    const float* src = wl[l] + r * 512 + k;
    float v[64];
    float m = -3.0e38f;
    #pragma unroll
    for (int c = 0; c < 64; ++c) { v[c] = src[c * 8]; m = fmaxf(m, v[c]); }
    float ssum = 0.f;
    #pragma unroll
    for (int c = 0; c < 64; ++c) { v[c] = __expf(v[c] - m); ssum += v[c]; }
    const float inv = 1.0f / ssum;
    float* dst = ws + base + r * 512 + k;
    #pragma unroll
    for (int c = 0; c < 64; ++c) dst[c * 8] = v[c] * inv;
  } else if (job < 2040 + 2048) {
    const int i = job - 2040;
    const float l = ls[i];
    ws[AOFF + i] = __expf(-l);
    ws[BOFF + i] = -l - HLP;
  } else if (job == 2040 + 2048) {
    float m = -3.0e38f;
    for (int k = 0; k < 8; ++k) m = fmaxf(m, root_w[k]);
    float e[8]; float ssum = 0.f;
    for (int k = 0; k < 8; ++k) { e[k] = __expf(root_w[k] - m); ssum += e[k]; }
    const float inv = 1.0f / ssum;
    for (int k = 0; k < 8; ++k) ws[ROFF + k] = e[k] * inv;
  }
}

// ---------------- main fused tree kernel ----------------
// LDS plane strides: odd and ==5 (mod 32) to spread banks. k-stride 9.
static constexpr int PLA = 128 * 9 + 5;  // 1157
static constexpr int PLB = 64 * 9 + 5;   // 581
static constexpr int NAO = 0;
static constexpr int NBO = TB * PLA;               // 9256
static constexpr int MAO = NBO + TB * PLB;         // 13904
static constexpr int MBO = MAO + TB * 128;         // 14928
static constexpr int SMEM_F = MBO + TB * 64;       // 15440 floats = 61760 B

__device__ __forceinline__ void mac64(const float* __restrict__ Wr,
                                      const float* na, const float* nb,
                                      float* s) {
  #pragma unroll
  for (int k = 0; k < 8; ++k) s[k] = 0.f;
  #pragma unroll
  for (int i = 0; i < 8; ++i) {
    const float ai = na[i];
    #pragma unroll
    for (int j = 0; j < 8; ++j) {
      const float e = ai * nb[j];
      const float4 wA = *reinterpret_cast<const float4*>(Wr + (i * 8 + j) * 8);
      const float4 wB = *reinterpret_cast<const float4*>(Wr + (i * 8 + j) * 8 + 4);
      s[0] = fmaf(e, wA.x, s[0]); s[1] = fmaf(e, wA.y, s[1]);
      s[2] = fmaf(e, wA.z, s[2]); s[3] = fmaf(e, wA.w, s[3]);
      s[4] = fmaf(e, wB.x, s[4]); s[5] = fmaf(e, wB.y, s[5]);
      s[6] = fmaf(e, wB.z, s[6]); s[7] = fmaf(e, wB.w, s[7]);
    }
  }
}

__device__ __forceinline__ float max8(const float* s) {
  float m = s[0];
  #pragma unroll
  for (int k = 1; k < 8; ++k) m = fmaxf(m, s[k]);
  return m;
}

__device__ __forceinline__ void leaf_eval(float xv,
                                          const float* __restrict__ mu8,
                                          const float* __restrict__ A8,
                                          const float* __restrict__ B8,
                                          float* n, float* M) {
  float h[8];
  float m = -3.0e38f;
  #pragma unroll
  for (int k = 0; k < 8; ++k) {
    const float z = (xv - mu8[k]) * A8[k];
    h[k] = fmaf(-0.5f * z, z, B8[k]);
    m = fmaxf(m, h[k]);
  }
  #pragma unroll
  for (int k = 0; k < 8; ++k) n[k] = __expf(h[k] - m);
  *M = m;
}

__global__ __launch_bounds__(NTH, 2) void spn_main(
    const float* __restrict__ x,
    const float* __restrict__ mu,
    const float* __restrict__ ws,
    float* __restrict__ out)
{
  const float* leafA = ws + AOFF;
  const float* leafB = ws + BOFF;
  const float* srw   = ws + ROFF;

  __shared__ float smem[SMEM_F];

  const int tid = threadIdx.x;
  const int bB = blockIdx.x * TB;

  // ---- Layer 0 (Gaussian leaves fused in) -> plane A (128 regions)
  {
    const float* W0 = ws;
    for (int it = tid; it < TB * 128; it += NTH) {
      const int bb = it & (TB - 1), r = it >> 3;
      float na[8], nb[8], Ma, Mb;
      const int f0 = 2 * r;
      const float xv0 = x[(bB + bb) * 256 + f0];
      const float xv1 = x[(bB + bb) * 256 + f0 + 1];
      leaf_eval(xv0, mu + f0 * 8, leafA + f0 * 8, leafB + f0 * 8, na, &Ma);
      leaf_eval(xv1, mu + f0 * 8 + 8, leafA + f0 * 8 + 8, leafB + f0 * 8 + 8, nb, &Mb);
      float s[8];
      mac64(W0 + r * 512, na, nb, s);
      const float smax = max8(s);
      const float inv = 1.0f / smax;
      const int ob = NAO + bb * PLA + r * 9;
      #pragma unroll
      for (int k = 0; k < 8; ++k) smem[ob + k] = s[k] * inv;
      smem[MAO + bb * 128 + r] = Ma + Mb + __logf(smax);
    }
  }
  __syncthreads();

  // ---- Layers 1..6 (generic ping-pong)
  int pinO = NAO, poutO = NBO;
  int MinO = MAO, MoutO = MBO;
  int PLIN = PLA, PLOUT = PLB;
  int Rin = 128;
  const float* Wl = ws + 128 * 512;
  for (int l = 1; l < 7; ++l) {
    const int Rout = Rin >> 1;
    for (int it = tid; it < TB * Rout; it += NTH) {
      const int bb = it & (TB - 1), r = it >> 3;
      float na[8], nb[8];
      const int ia = pinO + bb * PLIN + (2 * r) * 9;
      #pragma unroll
      for (int i = 0; i < 8; ++i) { na[i] = smem[ia + i]; nb[i] = smem[ia + 9 + i]; }
      float s[8];
      mac64(Wl + r * 512, na, nb, s);
      const float smax = max8(s);
      const float inv = 1.0f / smax;
      const int ob = poutO + bb * PLOUT + r * 9;
      #pragma unroll
      for (int k = 0; k < 8; ++k) smem[ob + k] = s[k] * inv;
      smem[MoutO + bb * Rout + r] =
          smem[MinO + bb * Rin + 2 * r] + smem[MinO + bb * Rin + 2 * r + 1] + __logf(smax);
    }
    __syncthreads();
    int t;
    t = pinO; pinO = poutO; poutO = t;
    t = MinO; MinO = MoutO; MoutO = t;
    t = PLIN; PLIN = PLOUT; PLOUT = t;
    Rin = Rout;
    Wl += Rout * 512;
  }

  // ---- Layer 7 + root logsumexp (Rin == 2, input in plane A)
  for (int it = tid; it < TB; it += NTH) {
    const int bb = it;
    float na[8], nb[8];
    const int ia = pinO + bb * PLIN;
    #pragma unroll
    for (int i = 0; i < 8; ++i) { na[i] = smem[ia + i]; nb[i] = smem[ia + 9 + i]; }
    float s[8];
    mac64(Wl, na, nb, s);
    float acc = 0.f;
    #pragma unroll
    for (int k = 0; k < 8; ++k) acc = fmaf(s[k], srw[k], acc);
    out[bB + bb] = smem[MinO + bb * 2] + smem[MinO + bb * 2 + 1] + __logf(acc);
  }
}

extern "C" void kernel_launch(void* const* d_in, const int* in_sizes, int n_in,
                              void* d_out, int out_size, void* d_ws, size_t ws_size,
                              hipStream_t stream) {
  const float* x      = (const float*)d_in[0];
  const float* mu     = (const float*)d_in[1];
  const float* ls     = (const float*)d_in[2];
  const float* w0     = (const float*)d_in[3];
  const float* w1     = (const float*)d_in[4];
  const float* w2     = (const float*)d_in[5];
  const float* w3     = (const float*)d_in[6];
  const float* w4     = (const float*)d_in[7];
  const float* w5     = (const float*)d_in[8];
  const float* w6     = (const float*)d_in[9];
  const float* w7     = (const float*)d_in[10];
  const float* root_w = (const float*)d_in[11];
  float* ws  = (float*)d_ws;
  float* out = (float*)d_out;

  spn_prep<<<16, 256, 0, stream>>>(ls, w0, w1, w2, w3, w4, w5, w6, w7, root_w, ws);
  spn_main<<<8192 / TB, 256, 0, stream>>>(x, mu, ws, out);
}